// Round 1
// baseline (1025.406 us; speedup 1.0000x reference)
//
#include <hip/hip_runtime.h>
#include <stdint.h>

#define B_TOK 8192
#define D_DIM 1024
#define H_DIM 4096
#define O_DIM 1024
#define E_NUM 8
#define K_TOP 2
#define NPAIR (B_TOK * K_TOP)   // 16384

typedef short bf16x8 __attribute__((ext_vector_type(8)));
typedef float f32x4 __attribute__((ext_vector_type(4)));

struct Hdr {
    int counts[8];
    int offsets[9];
    int cursor[8];
    int total1, total2;
    int base1[9];
    int base2[9];
};

__device__ __forceinline__ unsigned short f2bf(float f) {
    union { float f; unsigned int u; } v; v.f = f;
    unsigned int u = v.u;
    unsigned int r = (u + 0x7fffu + ((u >> 16) & 1u)) >> 16;
    return (unsigned short)r;
}

// async global->LDS, 16B per lane; LDS side lands at (wave-uniform base) + lane*16
__device__ __forceinline__ void async16(const void* g, const void* l) {
    __builtin_amdgcn_global_load_lds(
        (__attribute__((address_space(1))) void*)(uintptr_t)g,
        (__attribute__((address_space(3))) void*)(uint32_t)(uintptr_t)l,
        16, 0, 0);
}

// ---------------- conversion kernels ----------------

__global__ void cvt_x_kernel(const float* __restrict__ x, unsigned short* __restrict__ xb) {
    int i = (blockIdx.x * 256 + threadIdx.x) * 4;
    float4 v = *(const float4*)(x + i);
    ushort4 o;
    o.x = f2bf(v.x); o.y = f2bf(v.y); o.z = f2bf(v.z); o.w = f2bf(v.w);
    *(ushort4*)(xb + i) = o;
}

// in: [E][R][C] fp32 -> out: [E][C][R] bf16 (transpose + convert)
__global__ void tconv_kernel(const float* __restrict__ in, unsigned short* __restrict__ out,
                             int R, int C) {
    __shared__ float t[32][33];
    int e = blockIdx.z;
    const float* ip = in + (size_t)e * R * C;
    unsigned short* op = out + (size_t)e * R * C;
    int c0 = blockIdx.x * 32, r0 = blockIdx.y * 32;
    int tx = threadIdx.x, ty = threadIdx.y;
#pragma unroll
    for (int i = 0; i < 4; i++)
        t[ty + i * 8][tx] = ip[(size_t)(r0 + ty + i * 8) * C + c0 + tx];
    __syncthreads();
#pragma unroll
    for (int i = 0; i < 4; i++)
        op[(size_t)(c0 + ty + i * 8) * R + r0 + tx] = f2bf(t[tx][ty + i * 8]);
}

// ---------------- routing ----------------

__global__ void route_count_kernel(const int* __restrict__ topk, Hdr* hdr) {
    __shared__ int cnt[8];
    int tid = threadIdx.x;
    if (tid < 8) cnt[tid] = 0;
    __syncthreads();
    for (int i = tid; i < NPAIR; i += 1024) atomicAdd(&cnt[topk[i]], 1);
    __syncthreads();
    if (tid == 0) {
        int off = 0, t1 = 0, t2 = 0;
        for (int e = 0; e < 8; e++) {
            int c = cnt[e];
            hdr->counts[e] = c;
            hdr->offsets[e] = off;
            hdr->cursor[e] = off;
            hdr->base1[e] = t1;
            hdr->base2[e] = t2;
            int mt = (c + 127) >> 7;
            t1 += mt * (H_DIM / 128);
            t2 += mt * (O_DIM / 128);
            off += c;
        }
        hdr->offsets[8] = off;
        hdr->base1[8] = t1;
        hdr->base2[8] = t2;
        hdr->total1 = t1;
        hdr->total2 = t2;
    }
}

__global__ void route_fill_kernel(const int* __restrict__ topk, const float* __restrict__ wts,
                                  Hdr* hdr, int* __restrict__ ptok, float* __restrict__ pgate) {
    int i = blockIdx.x * 256 + threadIdx.x;
    int e = topk[i];
    int pos = atomicAdd(&hdr->cursor[e], 1);
    ptok[pos] = i >> 1;
    pgate[pos] = wts[i];
}

__global__ void ws_fail_kernel(float* out) { out[0] = 1.0e9f; }

// ---------------- grouped GEMM ----------------
// C[tile 128x128] = A[Mx K] * Bt[N x K]^T per expert segment.
// GATHER=true : A rows gathered via pair_token (GEMM1, x @ W1), epilogue relu->h (bf16)
// GATHER=false: A rows contiguous h slots (GEMM2, h @ W2), epilogue gate*(acc+b2) atomicAdd out
template <int K, int N, bool GATHER>
__global__ __launch_bounds__(256) void moe_gemm_kernel(
    const unsigned short* __restrict__ A,
    const unsigned short* __restrict__ Bt,
    const float* __restrict__ bias,
    const Hdr* __restrict__ hdr,
    const int* __restrict__ ptok,
    const float* __restrict__ pgate,
    unsigned short* __restrict__ hout,
    float* __restrict__ oout) {

    __shared__ __align__(16) unsigned short As[128 * 64];
    __shared__ __align__(16) unsigned short Bs[128 * 64];

    const int tid = threadIdx.x;
    const int lane = tid & 63;
    const int wv = tid >> 6;
    const int wu = __builtin_amdgcn_readfirstlane(wv);
    const int wm = (wv & 1) * 64;
    const int wn = (wv >> 1) * 64;
    const int lr = lane & 15;
    const int lkg = lane >> 4;

    const int total = GATHER ? hdr->total1 : hdr->total2;
    const int* tb = GATHER ? hdr->base1 : hdr->base2;
    constexpr int NT = N / 128;

    for (int t = blockIdx.x; t < total; t += gridDim.x) {
        int e = 0;
#pragma unroll
        for (int j = 1; j < 8; j++)
            if (t >= tb[j]) e = j;
        int local = t - tb[e];
        int mtile = local / NT, ntile = local % NT;
        int m0 = mtile * 128, n0 = ntile * 128;
        int cnt = hdr->counts[e], off = hdr->offsets[e];

        // staging source pointers: slot s = i*256+tid -> LDS row r=s/8, chunk col cs=s%8.
        // XOR swizzle on the GLOBAL side: the chunk stored at (r,cs) is logical chunk cs^(r&7).
        const unsigned short* gA[4];
        const unsigned short* gB[4];
#pragma unroll
        for (int i = 0; i < 4; i++) {
            int s = i * 256 + tid;
            int r = s >> 3;
            int cl = (s & 7) ^ (r & 7);
            int p = off + m0 + r;
            p = p > NPAIR - 1 ? NPAIR - 1 : p;
            if (GATHER)
                gA[i] = A + (size_t)ptok[p] * K + cl * 8;
            else
                gA[i] = A + (size_t)p * K + cl * 8;
            gB[i] = Bt + (size_t)e * ((size_t)N * K) + (size_t)(n0 + r) * K + cl * 8;
        }

        f32x4 zero = {0.f, 0.f, 0.f, 0.f};
        f32x4 acc[4][4];
#pragma unroll
        for (int mt = 0; mt < 4; mt++)
#pragma unroll
            for (int nt = 0; nt < 4; nt++) acc[mt][nt] = zero;

        for (int k0 = 0; k0 < K; k0 += 64) {
#pragma unroll
            for (int i = 0; i < 4; i++) {
                async16(gA[i] + k0, &As[(i * 256 + wu * 64) * 8]);
                async16(gB[i] + k0, &Bs[(i * 256 + wu * 64) * 8]);
            }
            __syncthreads();
#pragma unroll
            for (int ks = 0; ks < 2; ks++) {
                bf16x8 af[4], bfr[4];
#pragma unroll
                for (int q = 0; q < 4; q++) {
                    int ra = wm + q * 16 + lr;
                    int ca = (ks * 4 + lkg) ^ (ra & 7);
                    af[q] = *(const bf16x8*)&As[ra * 64 + ca * 8];
                    int rb = wn + q * 16 + lr;
                    int cb = (ks * 4 + lkg) ^ (rb & 7);
                    bfr[q] = *(const bf16x8*)&Bs[rb * 64 + cb * 8];
                }
#pragma unroll
                for (int mt = 0; mt < 4; mt++)
#pragma unroll
                    for (int nt = 0; nt < 4; nt++)
                        acc[mt][nt] = __builtin_amdgcn_mfma_f32_16x16x32_bf16(
                            af[mt], bfr[nt], acc[mt][nt], 0, 0, 0);
            }
            __syncthreads();
        }

        // epilogue. C/D layout: col = lane&15, row = (lane>>4)*4 + reg
        if constexpr (GATHER) {
#pragma unroll
            for (int nt = 0; nt < 4; nt++) {
                int n = n0 + wn + nt * 16 + lr;
                float bv = bias[(size_t)e * N + n];
#pragma unroll
                for (int mt = 0; mt < 4; mt++) {
#pragma unroll
                    for (int r2 = 0; r2 < 4; r2++) {
                        int m = m0 + wm + mt * 16 + lkg * 4 + r2;
                        if (m < cnt) {
                            float v = acc[mt][nt][r2] + bv;
                            v = v > 0.f ? v : 0.f;
                            hout[(size_t)(off + m) * N + n] = f2bf(v);
                        }
                    }
                }
            }
        } else {
#pragma unroll
            for (int mt = 0; mt < 4; mt++) {
#pragma unroll
                for (int r2 = 0; r2 < 4; r2++) {
                    int m = m0 + wm + mt * 16 + lkg * 4 + r2;
                    if (m < cnt) {
                        int slot = off + m;
                        float g = pgate[slot];
                        int tok = ptok[slot];
#pragma unroll
                        for (int nt = 0; nt < 4; nt++) {
                            int n = n0 + wn + nt * 16 + lr;
                            float v = g * (acc[mt][nt][r2] + bias[(size_t)e * N + n]);
                            atomicAdd(oout + (size_t)tok * N + n, v);
                        }
                    }
                }
            }
        }
    }
}

// ---------------- launch ----------------

extern "C" void kernel_launch(void* const* d_in, const int* in_sizes, int n_in,
                              void* d_out, int out_size, void* d_ws, size_t ws_size,
                              hipStream_t stream) {
    const float* x   = (const float*)d_in[0];
    const int* topk  = (const int*)d_in[1];
    const float* wts = (const float*)d_in[2];
    const float* W1  = (const float*)d_in[3];
    const float* b1  = (const float*)d_in[4];
    const float* W2  = (const float*)d_in[5];
    const float* b2  = (const float*)d_in[6];
    float* out = (float*)d_out;

    char* ws = (char*)d_ws;
    size_t off = 0;
    auto alloc = [&](size_t bytes) -> void* {
        void* p = ws + off;
        off += (bytes + 255) & ~(size_t)255;
        return p;
    };
    Hdr* hdr = (Hdr*)alloc(sizeof(Hdr));
    int* ptok = (int*)alloc((size_t)NPAIR * 4);
    float* pgate = (float*)alloc((size_t)NPAIR * 4);
    unsigned short* xb   = (unsigned short*)alloc((size_t)B_TOK * D_DIM * 2);
    unsigned short* W1bt = (unsigned short*)alloc((size_t)E_NUM * D_DIM * H_DIM * 2);
    unsigned short* W2bt = (unsigned short*)alloc((size_t)E_NUM * H_DIM * O_DIM * 2);
    unsigned short* hbuf = (unsigned short*)alloc((size_t)NPAIR * H_DIM * 2);

    if (off > ws_size) {
        // sentinel: workspace too small -> out[0]=1e9 so the failure mode is unmistakable
        hipMemsetAsync(d_out, 0, (size_t)out_size * sizeof(float), stream);
        ws_fail_kernel<<<1, 1, 0, stream>>>(out);
        return;
    }

    hipMemsetAsync(d_out, 0, (size_t)out_size * sizeof(float), stream);

    cvt_x_kernel<<<(B_TOK * D_DIM) / 1024, 256, 0, stream>>>(x, xb);
    tconv_kernel<<<dim3(H_DIM / 32, D_DIM / 32, E_NUM), dim3(32, 8), 0, stream>>>(W1, W1bt, D_DIM, H_DIM);
    tconv_kernel<<<dim3(O_DIM / 32, H_DIM / 32, E_NUM), dim3(32, 8), 0, stream>>>(W2, W2bt, H_DIM, O_DIM);
    route_count_kernel<<<1, 1024, 0, stream>>>(topk, hdr);
    route_fill_kernel<<<NPAIR / 256, 256, 0, stream>>>(topk, wts, hdr, ptok, pgate);

    moe_gemm_kernel<D_DIM, H_DIM, true><<<4608, 256, 0, stream>>>(
        xb, W1bt, b1, hdr, ptok, pgate, hbuf, nullptr);
    moe_gemm_kernel<H_DIM, O_DIM, false><<<1152, 256, 0, stream>>>(
        hbuf, W2bt, b2, hdr, ptok, pgate, nullptr, out);
}

// Round 2
// 858.687 us; speedup vs baseline: 1.1942x; 1.1942x over previous
//
#include <hip/hip_runtime.h>
#include <stdint.h>

#define B_TOK 8192
#define D_DIM 1024
#define H_DIM 4096
#define O_DIM 1024
#define E_NUM 8
#define K_TOP 2
#define NPAIR (B_TOK * K_TOP)   // 16384

typedef short bf16x8 __attribute__((ext_vector_type(8)));
typedef float f32x4 __attribute__((ext_vector_type(4)));

struct Hdr {
    int counts[8];
    int offsets[9];
    int cursor[8];
    int total1, total2;
    int base1[9];
    int base2[9];
};

__device__ __forceinline__ unsigned short f2bf(float f) {
    union { float f; unsigned int u; } v; v.f = f;
    unsigned int u = v.u;
    unsigned int r = (u + 0x7fffu + ((u >> 16) & 1u)) >> 16;
    return (unsigned short)r;
}

__device__ __forceinline__ float bf2f(unsigned short s) {
    union { unsigned int u; float f; } v;
    v.u = ((unsigned int)s) << 16;
    return v.f;
}

// async global->LDS, 16B per lane; LDS side lands at (wave-uniform base) + lane*16
__device__ __forceinline__ void async16(const void* g, const void* l) {
    __builtin_amdgcn_global_load_lds(
        (__attribute__((address_space(1))) void*)(uintptr_t)g,
        (__attribute__((address_space(3))) void*)(uint32_t)(uintptr_t)l,
        16, 0, 0);
}

// ---------------- conversion kernels ----------------

__global__ void cvt_x_kernel(const float* __restrict__ x, unsigned short* __restrict__ xb) {
    int i = (blockIdx.x * 256 + threadIdx.x) * 4;
    float4 v = *(const float4*)(x + i);
    ushort4 o;
    o.x = f2bf(v.x); o.y = f2bf(v.y); o.z = f2bf(v.z); o.w = f2bf(v.w);
    *(ushort4*)(xb + i) = o;
}

// in: [E][R][C] fp32 -> out: [E][C][R] bf16 (transpose + convert)
__global__ void tconv_kernel(const float* __restrict__ in, unsigned short* __restrict__ out,
                             int R, int C) {
    __shared__ float t[32][33];
    int e = blockIdx.z;
    const float* ip = in + (size_t)e * R * C;
    unsigned short* op = out + (size_t)e * R * C;
    int c0 = blockIdx.x * 32, r0 = blockIdx.y * 32;
    int tx = threadIdx.x, ty = threadIdx.y;
#pragma unroll
    for (int i = 0; i < 4; i++)
        t[ty + i * 8][tx] = ip[(size_t)(r0 + ty + i * 8) * C + c0 + tx];
    __syncthreads();
#pragma unroll
    for (int i = 0; i < 4; i++)
        op[(size_t)(c0 + ty + i * 8) * R + r0 + tx] = f2bf(t[tx][ty + i * 8]);
}

// ---------------- routing ----------------

__global__ void route_count_kernel(const int* __restrict__ topk, Hdr* hdr) {
    __shared__ int cnt[8];
    int tid = threadIdx.x;
    if (tid < 8) cnt[tid] = 0;
    __syncthreads();
    for (int i = tid; i < NPAIR; i += 1024) atomicAdd(&cnt[topk[i]], 1);
    __syncthreads();
    if (tid == 0) {
        int off = 0, t1 = 0, t2 = 0;
        for (int e = 0; e < 8; e++) {
            int c = cnt[e];
            hdr->counts[e] = c;
            hdr->offsets[e] = off;
            hdr->cursor[e] = off;
            hdr->base1[e] = t1;
            hdr->base2[e] = t2;
            int mt = (c + 127) >> 7;
            t1 += mt * (H_DIM / 128);
            t2 += mt * (O_DIM / 128);
            off += c;
        }
        hdr->offsets[8] = off;
        hdr->base1[8] = t1;
        hdr->base2[8] = t2;
        hdr->total1 = t1;
        hdr->total2 = t2;
    }
}

__global__ void route_fill_kernel(const int* __restrict__ topk, const float* __restrict__ wts,
                                  Hdr* hdr, int* __restrict__ ptok, float* __restrict__ pgate,
                                  int* __restrict__ pslot) {
    int i = blockIdx.x * 256 + threadIdx.x;
    int e = topk[i];
    int pos = atomicAdd(&hdr->cursor[e], 1);
    ptok[pos] = i >> 1;
    pgate[pos] = wts[i];
    pslot[i] = pos;
}

__global__ void ws_fail_kernel(float* out) { out[0] = 1.0e9f; }

// ---------------- grouped GEMM ----------------
// C[tile 128x128] = A[M x K] * Bt[N x K]^T per expert segment.
// GATHER=true : A rows gathered via pair_token (GEMM1, x @ W1), epilogue relu->h (bf16)
// GATHER=false: A rows contiguous h slots (GEMM2, h @ W2), epilogue (acc+b2)->bf16 oslot
template <int K, int N, bool GATHER>
__global__ __launch_bounds__(256, 3) void moe_gemm_kernel(
    const unsigned short* __restrict__ A,
    const unsigned short* __restrict__ Bt,
    const float* __restrict__ bias,
    const Hdr* __restrict__ hdr,
    const int* __restrict__ ptok,
    unsigned short* __restrict__ outp) {

    __shared__ __align__(16) unsigned short As[128 * 64];
    __shared__ __align__(16) unsigned short Bs[128 * 64];

    const int tid = threadIdx.x;
    const int lane = tid & 63;
    const int wv = tid >> 6;
    const int wu = __builtin_amdgcn_readfirstlane(wv);
    const int wm = (wv & 1) * 64;
    const int wn = (wv >> 1) * 64;
    const int lr = lane & 15;
    const int lkg = lane >> 4;

    const int total = GATHER ? hdr->total1 : hdr->total2;
    const int* tb = GATHER ? hdr->base1 : hdr->base2;
    constexpr int NT = N / 128;

    for (int t = blockIdx.x; t < total; t += gridDim.x) {
        int e = 0;
#pragma unroll
        for (int j = 1; j < 8; j++)
            if (t >= tb[j]) e = j;
        e = __builtin_amdgcn_readfirstlane(e);
        int local = t - tb[e];
        int mtile = local / NT, ntile = local % NT;
        int m0 = mtile * 128, n0 = ntile * 128;
        int cnt = hdr->counts[e], off = hdr->offsets[e];

        // staging: slot s = i*256+tid -> LDS row r=s/8, chunk col cs=s%8.
        // XOR swizzle on the GLOBAL side: chunk stored at (r,cs) is logical chunk cs^(r&7).
        // 32-bit BYTE offsets (A<=268MB? no: A,B each < 4GB) to save VGPRs.
        const char* Ab = (const char*)A;
        const char* Bb = (const char*)(Bt + (size_t)e * ((size_t)N * K));
        uint32_t offA[4], offB[4];
#pragma unroll
        for (int i = 0; i < 4; i++) {
            int s = i * 256 + tid;
            int r = s >> 3;
            int cl = (s & 7) ^ (r & 7);
            int p = off + m0 + r;
            p = p > NPAIR - 1 ? NPAIR - 1 : p;
            uint32_t row = GATHER ? (uint32_t)ptok[p] : (uint32_t)p;
            offA[i] = (row * (uint32_t)K + (uint32_t)cl * 8u) * 2u;
            offB[i] = (((uint32_t)(n0 + r)) * (uint32_t)K + (uint32_t)cl * 8u) * 2u;
        }

        f32x4 zero = {0.f, 0.f, 0.f, 0.f};
        f32x4 acc[4][4];
#pragma unroll
        for (int mt = 0; mt < 4; mt++)
#pragma unroll
            for (int nt = 0; nt < 4; nt++) acc[mt][nt] = zero;

        for (int k0 = 0; k0 < K; k0 += 64) {
#pragma unroll
            for (int i = 0; i < 4; i++) {
                async16(Ab + offA[i], &As[(i * 256 + wu * 64) * 8]);
                async16(Bb + offB[i], &Bs[(i * 256 + wu * 64) * 8]);
                offA[i] += 128;
                offB[i] += 128;
            }
            __syncthreads();
#pragma unroll
            for (int ks = 0; ks < 2; ks++) {
                bf16x8 af[4];
#pragma unroll
                for (int q = 0; q < 4; q++) {
                    int ra = wm + q * 16 + lr;
                    int ca = (ks * 4 + lkg) ^ (ra & 7);
                    af[q] = *(const bf16x8*)&As[ra * 64 + ca * 8];
                }
#pragma unroll
                for (int nt = 0; nt < 4; nt++) {
                    int rb = wn + nt * 16 + lr;
                    int cb = (ks * 4 + lkg) ^ (rb & 7);
                    bf16x8 bfr = *(const bf16x8*)&Bs[rb * 64 + cb * 8];
#pragma unroll
                    for (int mt = 0; mt < 4; mt++)
                        acc[mt][nt] = __builtin_amdgcn_mfma_f32_16x16x32_bf16(
                            af[mt], bfr, acc[mt][nt], 0, 0, 0);
                }
            }
            __syncthreads();
        }

        // epilogue. C/D layout: col = lane&15, row = (lane>>4)*4 + reg
        if constexpr (GATHER) {
#pragma unroll
            for (int nt = 0; nt < 4; nt++) {
                int n = n0 + wn + nt * 16 + lr;
                float bv = bias[(size_t)e * N + n];
#pragma unroll
                for (int mt = 0; mt < 4; mt++) {
#pragma unroll
                    for (int r2 = 0; r2 < 4; r2++) {
                        int m = m0 + wm + mt * 16 + lkg * 4 + r2;
                        if (m < cnt) {
                            float v = acc[mt][nt][r2] + bv;
                            v = v > 0.f ? v : 0.f;
                            outp[(size_t)(off + m) * N + n] = f2bf(v);
                        }
                    }
                }
            }
        } else {
#pragma unroll
            for (int nt = 0; nt < 4; nt++) {
                int n = n0 + wn + nt * 16 + lr;
                float bv = bias[(size_t)e * N + n];
#pragma unroll
                for (int mt = 0; mt < 4; mt++) {
#pragma unroll
                    for (int r2 = 0; r2 < 4; r2++) {
                        int m = m0 + wm + mt * 16 + lkg * 4 + r2;
                        if (m < cnt)
                            outp[(size_t)(off + m) * N + n] = f2bf(acc[mt][nt][r2] + bv);
                    }
                }
            }
        }
    }
}

// out[tok] = g0 * oslot[pslot[2t]] + g1 * oslot[pslot[2t+1]]
__global__ void combine_kernel(const unsigned short* __restrict__ oslot,
                               const int* __restrict__ pslot,
                               const float* __restrict__ wts,
                               float* __restrict__ out) {
    int tok = blockIdx.x;
    int s0 = pslot[tok * 2], s1 = pslot[tok * 2 + 1];
    float g0 = wts[tok * 2], g1 = wts[tok * 2 + 1];
    int n = threadIdx.x * 4;
    ushort4 a = *(const ushort4*)&oslot[(size_t)s0 * O_DIM + n];
    ushort4 b = *(const ushort4*)&oslot[(size_t)s1 * O_DIM + n];
    float4 o;
    o.x = g0 * bf2f(a.x) + g1 * bf2f(b.x);
    o.y = g0 * bf2f(a.y) + g1 * bf2f(b.y);
    o.z = g0 * bf2f(a.z) + g1 * bf2f(b.z);
    o.w = g0 * bf2f(a.w) + g1 * bf2f(b.w);
    *(float4*)&out[(size_t)tok * O_DIM + n] = o;
}

// ---------------- launch ----------------

extern "C" void kernel_launch(void* const* d_in, const int* in_sizes, int n_in,
                              void* d_out, int out_size, void* d_ws, size_t ws_size,
                              hipStream_t stream) {
    const float* x   = (const float*)d_in[0];
    const int* topk  = (const int*)d_in[1];
    const float* wts = (const float*)d_in[2];
    const float* W1  = (const float*)d_in[3];
    const float* b1  = (const float*)d_in[4];
    const float* W2  = (const float*)d_in[5];
    const float* b2  = (const float*)d_in[6];
    float* out = (float*)d_out;

    char* ws = (char*)d_ws;
    size_t off = 0;
    auto alloc = [&](size_t bytes) -> void* {
        void* p = ws + off;
        off += (bytes + 255) & ~(size_t)255;
        return p;
    };
    Hdr* hdr = (Hdr*)alloc(sizeof(Hdr));
    int* ptok = (int*)alloc((size_t)NPAIR * 4);
    float* pgate = (float*)alloc((size_t)NPAIR * 4);
    int* pslot = (int*)alloc((size_t)NPAIR * 4);
    unsigned short* xb   = (unsigned short*)alloc((size_t)B_TOK * D_DIM * 2);
    unsigned short* W1bt = (unsigned short*)alloc((size_t)E_NUM * D_DIM * H_DIM * 2);
    unsigned short* W2bt = (unsigned short*)alloc((size_t)E_NUM * H_DIM * O_DIM * 2);
    unsigned short* hbuf = (unsigned short*)alloc((size_t)NPAIR * H_DIM * 2);
    // oslot aliases W1bt (dead after GEMM1): NPAIR*O_DIM*2 = 33.5MB < 67MB
    unsigned short* oslot = W1bt;

    if (off > ws_size) {
        hipMemsetAsync(d_out, 0, (size_t)out_size * sizeof(float), stream);
        ws_fail_kernel<<<1, 1, 0, stream>>>(out);
        return;
    }

    cvt_x_kernel<<<(B_TOK * D_DIM) / 1024, 256, 0, stream>>>(x, xb);
    tconv_kernel<<<dim3(H_DIM / 32, D_DIM / 32, E_NUM), dim3(32, 8), 0, stream>>>(W1, W1bt, D_DIM, H_DIM);
    tconv_kernel<<<dim3(O_DIM / 32, H_DIM / 32, E_NUM), dim3(32, 8), 0, stream>>>(W2, W2bt, H_DIM, O_DIM);
    route_count_kernel<<<1, 1024, 0, stream>>>(topk, hdr);
    route_fill_kernel<<<NPAIR / 256, 256, 0, stream>>>(topk, wts, hdr, ptok, pgate, pslot);

    moe_gemm_kernel<D_DIM, H_DIM, true><<<4608, 256, 0, stream>>>(
        xb, W1bt, b1, hdr, ptok, hbuf);
    moe_gemm_kernel<H_DIM, O_DIM, false><<<1152, 256, 0, stream>>>(
        hbuf, W2bt, b2, hdr, ptok, oslot);
    combine_kernel<<<B_TOK, 256, 0, stream>>>(oslot, pslot, wts, out);
}

// Round 3
// 752.295 us; speedup vs baseline: 1.3630x; 1.1414x over previous
//
#include <hip/hip_runtime.h>
#include <stdint.h>

#define B_TOK 8192
#define D_DIM 1024
#define H_DIM 4096
#define O_DIM 1024
#define E_NUM 8
#define K_TOP 2
#define NPAIR (B_TOK * K_TOP)   // 16384

typedef short bf16x8 __attribute__((ext_vector_type(8)));
typedef float f32x4 __attribute__((ext_vector_type(4)));

struct Hdr {
    int counts[8];
    int offsets[9];
    int cursor[8];
    int total1, total2;
    int base1[9];
    int base2[9];
};

__device__ __forceinline__ unsigned short f2bf(float f) {
    union { float f; unsigned int u; } v; v.f = f;
    unsigned int u = v.u;
    unsigned int r = (u + 0x7fffu + ((u >> 16) & 1u)) >> 16;
    return (unsigned short)r;
}

__device__ __forceinline__ float bf2f(unsigned short s) {
    union { unsigned int u; float f; } v;
    v.u = ((unsigned int)s) << 16;
    return v.f;
}

// async global->LDS, 16B per lane; LDS side lands at (wave-uniform base) + lane*16
__device__ __forceinline__ void async16(const void* g, const void* l) {
    __builtin_amdgcn_global_load_lds(
        (__attribute__((address_space(1))) void*)(uintptr_t)g,
        (__attribute__((address_space(3))) void*)(uint32_t)(uintptr_t)l,
        16, 0, 0);
}

// ---------------- conversion kernels ----------------

__global__ void cvt_x_kernel(const float* __restrict__ x, unsigned short* __restrict__ xb) {
    int i = (blockIdx.x * 256 + threadIdx.x) * 4;
    float4 v = *(const float4*)(x + i);
    ushort4 o;
    o.x = f2bf(v.x); o.y = f2bf(v.y); o.z = f2bf(v.z); o.w = f2bf(v.w);
    *(ushort4*)(xb + i) = o;
}

// in: [E][R][C] fp32 -> out: [E][C][R] bf16 (transpose + convert), 64x64 tiles
// pad 69: both LDS phases measured-free bank patterns (32 banks, 2-way max)
__global__ __launch_bounds__(256) void tconv_kernel(const float* __restrict__ in,
                                                    unsigned short* __restrict__ out,
                                                    int R, int C) {
    __shared__ float t[64 * 69];
    int e = blockIdx.z;
    const float* ip = in + (size_t)e * R * C;
    unsigned short* op = out + (size_t)e * R * C;
    int c0 = blockIdx.x * 64, r0 = blockIdx.y * 64;
    int tid = threadIdx.x;
    int lr = tid >> 4;          // 0..15
    int lc = (tid & 15) * 4;    // 0..60
#pragma unroll
    for (int i = 0; i < 4; i++) {
        int row = lr + i * 16;
        float4 v = *(const float4*)&ip[(size_t)(r0 + row) * C + c0 + lc];
        t[row * 69 + lc + 0] = v.x;
        t[row * 69 + lc + 1] = v.y;
        t[row * 69 + lc + 2] = v.z;
        t[row * 69 + lc + 3] = v.w;
    }
    __syncthreads();
#pragma unroll
    for (int i = 0; i < 4; i++) {
        int c = lr + i * 16;
        ushort4 o;
        o.x = f2bf(t[(lc + 0) * 69 + c]);
        o.y = f2bf(t[(lc + 1) * 69 + c]);
        o.z = f2bf(t[(lc + 2) * 69 + c]);
        o.w = f2bf(t[(lc + 3) * 69 + c]);
        *(ushort4*)&op[(size_t)(c0 + c) * R + r0 + lc] = o;
    }
}

// ---------------- routing ----------------

__global__ void route_count_kernel(const int* __restrict__ topk, Hdr* hdr) {
    __shared__ int cnt[8];
    int tid = threadIdx.x;
    if (tid < 8) cnt[tid] = 0;
    __syncthreads();
    for (int i = tid; i < NPAIR; i += 1024) atomicAdd(&cnt[topk[i]], 1);
    __syncthreads();
    if (tid == 0) {
        int off = 0, t1 = 0, t2 = 0;
        for (int e = 0; e < 8; e++) {
            int c = cnt[e];
            hdr->counts[e] = c;
            hdr->offsets[e] = off;
            hdr->cursor[e] = off;
            hdr->base1[e] = t1;
            hdr->base2[e] = t2;
            int mt = (c + 127) >> 7;
            t1 += mt * (H_DIM / 128);
            t2 += mt * (O_DIM / 128);
            off += c;
        }
        hdr->offsets[8] = off;
        hdr->base1[8] = t1;
        hdr->base2[8] = t2;
        hdr->total1 = t1;
        hdr->total2 = t2;
    }
}

__global__ void route_fill_kernel(const int* __restrict__ topk, const float* __restrict__ wts,
                                  Hdr* hdr, int* __restrict__ ptok, float* __restrict__ pgate,
                                  int* __restrict__ pslot) {
    int i = blockIdx.x * 256 + threadIdx.x;
    int e = topk[i];
    int pos = atomicAdd(&hdr->cursor[e], 1);
    ptok[pos] = i >> 1;
    pgate[pos] = wts[i];
    pslot[i] = pos;
}

__global__ void ws_fail_kernel(float* out) { out[0] = 1.0e9f; }

// ---------------- grouped GEMM ----------------
// C[tile 128x128] = A[M x K] * Bt[N x K]^T per expert segment.
// Tile order: XCD-chunked (blockIdx%8 = XCD gets contiguous seq range) + 8x8
// supertile (64 consecutive seq share 8 A-tiles + 8 B-tiles = 4MB = one XCD L2).
// Epilogue: C tile -> LDS (bf16, row stride 132 = conflict-free b16 writes),
// then 256B-coalesced row stores.
template <int K, int N, bool GATHER>
__global__ __launch_bounds__(256, 4) void moe_gemm_kernel(
    const unsigned short* __restrict__ A,
    const unsigned short* __restrict__ Bt,
    const float* __restrict__ bias,
    const Hdr* __restrict__ hdr,
    const int* __restrict__ ptok,
    unsigned short* __restrict__ outp) {

    // staging: As = smem[0:8192), Bs = smem[8192:16384); epilogue: 128 x 132
    __shared__ __align__(16) unsigned short smem[128 * 132];
    unsigned short* As = smem;
    unsigned short* Bs = smem + 128 * 64;

    const int tid = threadIdx.x;
    const int lane = tid & 63;
    const int wv = tid >> 6;
    const int wu = __builtin_amdgcn_readfirstlane(wv);
    const int wm = (wv & 1) * 64;
    const int wn = (wv >> 1) * 64;
    const int lr = lane & 15;
    const int lkg = lane >> 4;

    const int total = GATHER ? hdr->total1 : hdr->total2;
    const int* tb = GATHER ? hdr->base1 : hdr->base2;
    constexpr int NT = N / 128;

    int chunk = (total + 7) >> 3;
    int seq = (blockIdx.x & 7) * chunk + (blockIdx.x >> 3);
    if (seq >= total) return;

    int e = 0;
#pragma unroll
    for (int j = 1; j < 8; j++)
        if (seq >= tb[j]) e = j;
    e = __builtin_amdgcn_readfirstlane(e);
    int lt = seq - tb[e];
    int cnt = hdr->counts[e], off = hdr->offsets[e];
    int MT = (cnt + 127) >> 7;

    // 8x8 supertile decode (m fastest within group -> consecutive blocks share B)
    int band = lt / (NT * 8);
    int r = lt - band * (NT * 8);
    int mrem = MT - band * 8;
    mrem = mrem > 8 ? 8 : mrem;
    int gsz = mrem * 8;
    int g = r / gsz;
    int rg = r - g * gsz;
    int gm = rg % mrem;
    int gn = rg / mrem;
    int mtile = band * 8 + gm;
    int ntile = g * 8 + gn;
    int m0 = mtile * 128, n0 = ntile * 128;

    // staging: slot s = i*256+tid -> LDS row r=s/8, chunk col cs=s%8.
    // XOR swizzle on the GLOBAL side: chunk stored at (r,cs) is logical cs^(r&7).
    const char* Ab = (const char*)A;
    const char* Bb = (const char*)(Bt + (size_t)e * ((size_t)N * K));
    uint32_t offA[4], offB[4];
#pragma unroll
    for (int i = 0; i < 4; i++) {
        int s = i * 256 + tid;
        int rr = s >> 3;
        int cl = (s & 7) ^ (rr & 7);
        int p = off + m0 + rr;
        p = p > NPAIR - 1 ? NPAIR - 1 : p;
        uint32_t row = GATHER ? (uint32_t)ptok[p] : (uint32_t)p;
        offA[i] = (row * (uint32_t)K + (uint32_t)cl * 8u) * 2u;
        offB[i] = (((uint32_t)(n0 + rr)) * (uint32_t)K + (uint32_t)cl * 8u) * 2u;
    }

    f32x4 zero = {0.f, 0.f, 0.f, 0.f};
    f32x4 acc[4][4];
#pragma unroll
    for (int mt = 0; mt < 4; mt++)
#pragma unroll
        for (int nt = 0; nt < 4; nt++) acc[mt][nt] = zero;

    for (int k0 = 0; k0 < K; k0 += 64) {
#pragma unroll
        for (int i = 0; i < 4; i++) {
            async16(Ab + offA[i], &As[(i * 256 + wu * 64) * 8]);
            async16(Bb + offB[i], &Bs[(i * 256 + wu * 64) * 8]);
            offA[i] += 128;
            offB[i] += 128;
        }
        __syncthreads();
#pragma unroll
        for (int ks = 0; ks < 2; ks++) {
            bf16x8 af[4];
#pragma unroll
            for (int q = 0; q < 4; q++) {
                int ra = wm + q * 16 + lr;
                int ca = (ks * 4 + lkg) ^ (ra & 7);
                af[q] = *(const bf16x8*)&As[ra * 64 + ca * 8];
            }
#pragma unroll
            for (int nt = 0; nt < 4; nt++) {
                int rb = wn + nt * 16 + lr;
                int cb = (ks * 4 + lkg) ^ (rb & 7);
                bf16x8 bfr = *(const bf16x8*)&Bs[rb * 64 + cb * 8];
#pragma unroll
                for (int mt = 0; mt < 4; mt++)
                    acc[mt][nt] = __builtin_amdgcn_mfma_f32_16x16x32_bf16(
                        af[mt], bfr, acc[mt][nt], 0, 0, 0);
            }
        }
        __syncthreads();
    }

    // ---- epilogue: stage C to LDS (row stride 132), then coalesced stores ----
    // C/D layout: col = lane&15, row = (lane>>4)*4 + reg
#pragma unroll
    for (int nt = 0; nt < 4; nt++) {
        int n = wn + nt * 16 + lr;
        float bv = bias[(size_t)e * N + n0 + n];
#pragma unroll
        for (int mt = 0; mt < 4; mt++) {
#pragma unroll
            for (int r2 = 0; r2 < 4; r2++) {
                int m = wm + mt * 16 + lkg * 4 + r2;
                float v = acc[mt][nt][r2] + bv;
                if (GATHER) v = v > 0.f ? v : 0.f;
                smem[m * 132 + n] = f2bf(v);
            }
        }
    }
    __syncthreads();
    int rows_valid = cnt - m0;
    if (rows_valid > 128) rows_valid = 128;
#pragma unroll
    for (int j = 0; j < 16; j++) {
        int idx = j * 256 + tid;
        int row = idx >> 5;        // 0..127, 32 lanes per row
        int lc8 = idx & 31;        // 8-byte units across 128 cols
        if (row < rows_valid) {
            uint2 v = *(const uint2*)&smem[row * 132 + lc8 * 4];
            *(uint2*)&outp[(size_t)(off + m0 + row) * N + n0 + lc8 * 4] = v;
        }
    }
}

// out[tok] = g0 * oslot[pslot[2t]] + g1 * oslot[pslot[2t+1]]
__global__ void combine_kernel(const unsigned short* __restrict__ oslot,
                               const int* __restrict__ pslot,
                               const float* __restrict__ wts,
                               float* __restrict__ out) {
    int tok = blockIdx.x;
    int s0 = pslot[tok * 2], s1 = pslot[tok * 2 + 1];
    float g0 = wts[tok * 2], g1 = wts[tok * 2 + 1];
    int n = threadIdx.x * 4;
    ushort4 a = *(const ushort4*)&oslot[(size_t)s0 * O_DIM + n];
    ushort4 b = *(const ushort4*)&oslot[(size_t)s1 * O_DIM + n];
    float4 o;
    o.x = g0 * bf2f(a.x) + g1 * bf2f(b.x);
    o.y = g0 * bf2f(a.y) + g1 * bf2f(b.y);
    o.z = g0 * bf2f(a.z) + g1 * bf2f(b.z);
    o.w = g0 * bf2f(a.w) + g1 * bf2f(b.w);
    *(float4*)&out[(size_t)tok * O_DIM + n] = o;
}

// ---------------- launch ----------------

extern "C" void kernel_launch(void* const* d_in, const int* in_sizes, int n_in,
                              void* d_out, int out_size, void* d_ws, size_t ws_size,
                              hipStream_t stream) {
    const float* x   = (const float*)d_in[0];
    const int* topk  = (const int*)d_in[1];
    const float* wts = (const float*)d_in[2];
    const float* W1  = (const float*)d_in[3];
    const float* b1  = (const float*)d_in[4];
    const float* W2  = (const float*)d_in[5];
    const float* b2  = (const float*)d_in[6];
    float* out = (float*)d_out;

    char* ws = (char*)d_ws;
    size_t off = 0;
    auto alloc = [&](size_t bytes) -> void* {
        void* p = ws + off;
        off += (bytes + 255) & ~(size_t)255;
        return p;
    };
    Hdr* hdr = (Hdr*)alloc(sizeof(Hdr));
    int* ptok = (int*)alloc((size_t)NPAIR * 4);
    float* pgate = (float*)alloc((size_t)NPAIR * 4);
    int* pslot = (int*)alloc((size_t)NPAIR * 4);
    unsigned short* xb   = (unsigned short*)alloc((size_t)B_TOK * D_DIM * 2);
    unsigned short* W1bt = (unsigned short*)alloc((size_t)E_NUM * D_DIM * H_DIM * 2);
    unsigned short* W2bt = (unsigned short*)alloc((size_t)E_NUM * H_DIM * O_DIM * 2);
    unsigned short* hbuf = (unsigned short*)alloc((size_t)NPAIR * H_DIM * 2);
    // oslot aliases W1bt (dead after GEMM1): NPAIR*O_DIM*2 = 33.5MB < 67MB
    unsigned short* oslot = W1bt;

    if (off > ws_size) {
        hipMemsetAsync(d_out, 0, (size_t)out_size * sizeof(float), stream);
        ws_fail_kernel<<<1, 1, 0, stream>>>(out);
        return;
    }

    cvt_x_kernel<<<(B_TOK * D_DIM) / 1024, 256, 0, stream>>>(x, xb);
    tconv_kernel<<<dim3(H_DIM / 64, D_DIM / 64, E_NUM), dim3(256), 0, stream>>>(W1, W1bt, D_DIM, H_DIM);
    tconv_kernel<<<dim3(O_DIM / 64, H_DIM / 64, E_NUM), dim3(256), 0, stream>>>(W2, W2bt, H_DIM, O_DIM);
    route_count_kernel<<<1, 1024, 0, stream>>>(topk, hdr);
    route_fill_kernel<<<NPAIR / 256, 256, 0, stream>>>(topk, wts, hdr, ptok, pgate, pslot);

    moe_gemm_kernel<D_DIM, H_DIM, true><<<4608, 256, 0, stream>>>(
        xb, W1bt, b1, hdr, ptok, hbuf);
    moe_gemm_kernel<H_DIM, O_DIM, false><<<1152, 256, 0, stream>>>(
        hbuf, W2bt, b2, hdr, ptok, oslot);
    combine_kernel<<<B_TOK, 256, 0, stream>>>(oslot, pslot, wts, out);
}